// Round 1
// baseline (656.196 us; speedup 1.0000x reference)
//
#include <hip/hip_runtime.h>
#include <hip/hip_bf16.h>

// Dipole: day-emb GEMM -> fwd GRU + 64 reverse GRUs -> masked softmax attention -> 2-layer head.
// T=64 B=32 D_IN=4096 D_DAY=H=256 D_OUT=942.
//
// Plan:
//  k1 pack_all      : repack all weights to bf16 MFMA B-fragment layout (one kernel).
//  k2 gemm<0>       : day_emb = x @ W_emb^T + b_emb            (2048x4096x256, bf16 out)
//  k3 gemm<1>       : Gi = day_emb @ [Wih_r|Wih_f]^T + bih     (2048x256x1536, fp32 out)
//  k4 gru_recurrent : 128 reverse WGs (anchor i, 16 rows, i+1 steps) + 2 forward WGs.
//                     Whh in registers as B-frags; h state fp32 in VGPRs; bf16 h via LDS dbuf.
//  k5 attn          : per-(i,b) wave: online softmax over t<=i; writes h_t = [c_f|c_r|fwd|rev_last]
//  k6 gemm<2>       : tmp = h_t @ W_ao^T + b_ao                (2048x1024x256, bf16 out)
//  k7 gemm<3>       : out = sigmoid(tmp @ W_o^T + b_o)         (2048x256x942, fp32 out)

typedef __bf16 bf16x8 __attribute__((ext_vector_type(8)));
typedef __bf16 bf16x4 __attribute__((ext_vector_type(4)));
typedef float  f32x4  __attribute__((ext_vector_type(4)));

// ---------------- workspace layout (bytes) ----------------
static constexpr size_t OFF_PK_EMB = 0;                        // 256x4096 bf16    = 2097152
static constexpr size_t OFF_PK_IH  = 2097152;                  // 1536x256 bf16    =  786432
static constexpr size_t OFF_PK_HHR = 2883584;                  // 768x256 bf16     =  393216
static constexpr size_t OFF_PK_HHF = 3276800;                  // 768x256 bf16     =  393216
static constexpr size_t OFF_PK_AO  = 3670016;                  // 256x1024 bf16    =  524288
static constexpr size_t OFF_PK_O   = 4194304;                  // 960x256 bf16     =  491520
static constexpr size_t OFF_DAY    = 4685824;                  // 2048x256 bf16    = 1048576
static constexpr size_t OFF_GI     = 5734400;                  // 2048x1536 f32    = 12582912
static constexpr size_t OFF_REV    = 18317312;                 // 2080*32*256 bf16 = 34078720
static constexpr size_t OFF_FWD    = 52396032;                 // 64*32*256 bf16   = 1048576
static constexpr size_t OFF_HT     = 53444608;                 // 2048x1024 bf16   = 4194304
static constexpr size_t OFF_TMP1   = 57638912;                 // 2048x256 bf16    = 1048576
// total ~58.7 MB

__device__ __forceinline__ float sigf(float x)  { return 1.f / (1.f + __expf(-x)); }
__device__ __forceinline__ float tanhf_(float x){ return 1.f - 2.f / (__expf(2.f*x) + 1.f); }

// ---------------- weight packer ----------------
// dst frag layout (per 16x16x32 mfma B operand): element
//   flat = ((nt*K32 + ks)*64 + lane)*8 + j  holds  W[nt*16 + lane%16][ks*32 + (lane/16)*8 + j]
__global__ __launch_bounds__(256) void pack_all(
    const float* __restrict__ We,  const float* __restrict__ Wir, const float* __restrict__ Wif,
    const float* __restrict__ Whr, const float* __restrict__ Whf, const float* __restrict__ Wao,
    const float* __restrict__ Wo,
    __bf16* pe, __bf16* pi, __bf16* phr, __bf16* phf, __bf16* pao, __bf16* po)
{
    int b = blockIdx.x;
    const float* src; __bf16* dst; int Nsrc, k32l, b0;
    if (b < 4096)      { src = We;  dst = pe;          Nsrc = 256; k32l = 7; b0 = 0;    }
    else if (b < 4864) { src = Wir; dst = pi;          Nsrc = 768; k32l = 3; b0 = 4096; }
    else if (b < 5632) { src = Wif; dst = pi + 196608; Nsrc = 768; k32l = 3; b0 = 4864; }
    else if (b < 6400) { src = Whr; dst = phr;         Nsrc = 768; k32l = 3; b0 = 5632; }
    else if (b < 7168) { src = Whf; dst = phf;         Nsrc = 768; k32l = 3; b0 = 6400; }
    else if (b < 8192) { src = Wao; dst = pao;         Nsrc = 256; k32l = 5; b0 = 7168; }
    else               { src = Wo;  dst = po;          Nsrc = 942; k32l = 3; b0 = 8192; }
    int e    = (b - b0) * 256 + threadIdx.x;
    int j    = e & 7;
    int lane = (e >> 3) & 63;
    int K32  = 1 << k32l;
    int K    = K32 << 5;
    int ks   = (e >> 9) & (K32 - 1);
    int nt   = e >> (9 + k32l);
    int n    = nt * 16 + (lane & 15);
    int k    = ks * 32 + ((lane >> 4) << 3) + j;
    float v  = (n < Nsrc) ? src[(size_t)n * K + k] : 0.f;
    dst[e] = (__bf16)v;
}

// ---------------- generic MFMA GEMM: C[M x N] = A[M x K] @ W^T (+bias) ----------------
// MODE 0: A fp32 (x),   out bf16 (day_emb)
// MODE 1: A bf16 (day), out fp32 (Gi), bias split r/f
// MODE 2: A bf16 (h_t), out bf16 (tmp1)
// MODE 3: A bf16 (tmp), out fp32 sigmoid, masked to NREAL cols
template<int MODE, int KDIM, int CSTRIDE, int NREAL>
__global__ __launch_bounds__(256) void gemm_k(
    const void* __restrict__ Ap, const __bf16* __restrict__ Bp, void* __restrict__ Cp,
    const float* __restrict__ bias, const float* __restrict__ bias2)
{
    __shared__ __align__(16) __bf16 As[64][88];   // stride 88 -> 2-way-max LDS conflicts
    const int tid = threadIdx.x;
    const int w = tid >> 6, lane = tid & 63, c = lane & 15, quad = lane >> 4;
    const int mb = blockIdx.x, nb = blockIdx.y;
    constexpr int K32 = KDIM / 32;
    constexpr int NK  = KDIM / 64;

    f32x4 acc[4];
#pragma unroll
    for (int nt = 0; nt < 4; nt++) acc[nt] = (f32x4){0.f, 0.f, 0.f, 0.f};

    const int row = tid >> 2, kp = (tid & 3) * 16;
    float4 pf[4]; uint4 pb[2];

    auto issue = [&](int kb) {
        if constexpr (MODE == 0) {
            const float* ap = (const float*)Ap + (size_t)(mb * 64 + row) * KDIM + kb * 64 + kp;
            pf[0] = ((const float4*)ap)[0]; pf[1] = ((const float4*)ap)[1];
            pf[2] = ((const float4*)ap)[2]; pf[3] = ((const float4*)ap)[3];
        } else {
            const __bf16* ap = (const __bf16*)Ap + (size_t)(mb * 64 + row) * KDIM + kb * 64 + kp;
            pb[0] = ((const uint4*)ap)[0]; pb[1] = ((const uint4*)ap)[1];
        }
    };
    auto commit = [&]() {
        if constexpr (MODE == 0) {
            __bf16 t[16];
#pragma unroll
            for (int q = 0; q < 4; q++) {
                t[q*4+0] = (__bf16)pf[q].x; t[q*4+1] = (__bf16)pf[q].y;
                t[q*4+2] = (__bf16)pf[q].z; t[q*4+3] = (__bf16)pf[q].w;
            }
            *(uint4*)&As[row][kp]     = *(uint4*)&t[0];
            *(uint4*)&As[row][kp + 8] = *(uint4*)&t[8];
        } else {
            *(uint4*)&As[row][kp]     = pb[0];
            *(uint4*)&As[row][kp + 8] = pb[1];
        }
    };

    issue(0);
    for (int kb = 0; kb < NK; kb++) {
        commit();
        __syncthreads();
        if (kb + 1 < NK) issue(kb + 1);   // prefetch next A block; latency hidden by MFMA
#pragma unroll
        for (int kk = 0; kk < 2; kk++) {
            bf16x8 a = *(const bf16x8*)&As[w * 16 + c][kk * 32 + quad * 8];
#pragma unroll
            for (int nt = 0; nt < 4; nt++) {
                bf16x8 bfr = *(const bf16x8*)(Bp +
                    ((size_t)((nb * 4 + nt) * K32 + kb * 2 + kk) * 64 + lane) * 8);
                acc[nt] = __builtin_amdgcn_mfma_f32_16x16x32_bf16(a, bfr, acc[nt], 0, 0, 0);
            }
        }
        __syncthreads();
    }

#pragma unroll
    for (int nt = 0; nt < 4; nt++) {
        int n = nb * 64 + nt * 16 + c;
        float bv;
        if constexpr (MODE == 1) bv = (n < 768) ? bias[n] : bias2[n - 768];
        else                     bv = (n < NREAL) ? bias[n] : 0.f;
#pragma unroll
        for (int r0 = 0; r0 < 4; r0++) {
            int m = mb * 64 + w * 16 + quad * 4 + r0;
            float v = acc[nt][r0] + bv;
            if constexpr (MODE == 0)      ((__bf16*)Cp)[(size_t)m * CSTRIDE + n] = (__bf16)v;
            else if constexpr (MODE == 1) ((float*)Cp)[(size_t)m * CSTRIDE + n] = v;
            else if constexpr (MODE == 2) ((__bf16*)Cp)[(size_t)m * CSTRIDE + n] = (__bf16)v;
            else { if (n < NREAL) ((float*)Cp)[(size_t)m * CSTRIDE + n] = sigf(v); }
        }
    }
}

// ---------------- recurrent GRU kernel ----------------
// grid = 130 x 1024 threads (16 waves).
// bid 0..127: reverse anchor i = bid>>1, batch rows b0 = (bid&1)*16, runs i+1 steps,
//             input index t_in = i - j, writes rev[triangular(i) + (j*32+b)*256 + d].
// bid 128/129: forward GRU halves, 64 steps, input t_in = j, writes fwd.
// Wave w owns h-dims [16w,16w+16); its 3 acc tiles (r/z/n gate cols g*256+16w..+16)
// line up with the mfma C layout (col=lane&15,row=quad*4+reg) so the GRU cell is in-register.
__global__ __launch_bounds__(1024) void gru_recurrent(
    const __bf16* __restrict__ pk_hh_r, const __bf16* __restrict__ pk_hh_f,
    const float* __restrict__ bhh_r, const float* __restrict__ bhh_f,
    const float* __restrict__ Gi,
    __bf16* __restrict__ revb, __bf16* __restrict__ fwdb)
{
    __shared__ __align__(16) __bf16 hbuf[2][16][264];  // stride 264: 16B-aligned, 2-way banks
    const int tid = threadIdx.x;
    const int w = tid >> 6, lane = tid & 63, c = lane & 15, quad = lane >> 4;
    const int bid = blockIdx.x;
    const bool isF = (bid >= 128);
    const int ia = isF ? 63 : (bid >> 1);
    const int b0 = isF ? ((bid - 128) << 4) : ((bid & 1) << 4);
    const int steps = ia + 1;
    const __bf16* pk = isF ? pk_hh_f : pk_hh_r;
    const float* bhh = isF ? bhh_f : bhh_r;
    const int gcol = isF ? 768 : 0;
    __bf16* outb = isF ? fwdb : (revb + ((size_t)(ia * (ia + 1) / 2)) * 8192);
    const int d = (w << 4) + c;

    // Whh B-fragments -> registers (24 x 16B per lane = 96 VGPRs)
    bf16x8 bw[24];
#pragma unroll
    for (int g = 0; g < 3; g++)
#pragma unroll
        for (int kk = 0; kk < 8; kk++)
            bw[g * 8 + kk] = *(const bf16x8*)(pk + (((size_t)((g * 16 + w) * 8 + kk)) * 64 + lane) * 8);
    float bhv[3];
#pragma unroll
    for (int g = 0; g < 3; g++) bhv[g] = bhh[g * 256 + d];

    float hreg[4] = {0.f, 0.f, 0.f, 0.f};
    for (int idx = tid; idx < 2 * 16 * 264; idx += 1024) ((__bf16*)hbuf)[idx] = (__bf16)0.f;
    __syncthreads();

    for (int j = 0; j < steps; j++) {
        const int t_in = isF ? j : (ia - j);
        const int rb = j & 1, wbuf = rb ^ 1;

        // input-side gates (precomputed, fp32); issued early, consumed after MFMA
        const float* gp = Gi + (size_t)(t_in * 32 + b0 + quad * 4) * 1536 + gcol + d;
        float gir[4], giz[4], gin[4];
#pragma unroll
        for (int r0 = 0; r0 < 4; r0++) {
            gir[r0] = gp[(size_t)r0 * 1536];
            giz[r0] = gp[(size_t)r0 * 1536 + 256];
            gin[r0] = gp[(size_t)r0 * 1536 + 512];
        }

        f32x4 a0 = {0,0,0,0}, a1 = {0,0,0,0}, a2 = {0,0,0,0};
#pragma unroll
        for (int kk = 0; kk < 8; kk++) {
            bf16x8 av = *(const bf16x8*)&hbuf[rb][c][kk * 32 + quad * 8];
            a0 = __builtin_amdgcn_mfma_f32_16x16x32_bf16(av, bw[kk],      a0, 0, 0, 0);
            a1 = __builtin_amdgcn_mfma_f32_16x16x32_bf16(av, bw[8 + kk],  a1, 0, 0, 0);
            a2 = __builtin_amdgcn_mfma_f32_16x16x32_bf16(av, bw[16 + kk], a2, 0, 0, 0);
        }

        __bf16* go = outb + (size_t)(j * 32 + b0 + quad * 4) * 256 + d;
#pragma unroll
        for (int r0 = 0; r0 < 4; r0++) {
            float rg = sigf(a0[r0] + bhv[0] + gir[r0]);
            float zg = sigf(a1[r0] + bhv[1] + giz[r0]);
            float ng = tanhf_(gin[r0] + rg * (a2[r0] + bhv[2]));
            float h  = (1.f - zg) * ng + zg * hreg[r0];
            hreg[r0] = h;
            __bf16 hb = (__bf16)h;
            hbuf[wbuf][quad * 4 + r0][d] = hb;   // broadcast for next step's A-frags
            go[(size_t)r0 * 256] = hb;           // persist state for attention
        }
        __syncthreads();
    }
}

// ---------------- attention (online softmax over t<=i) ----------------
__global__ __launch_bounds__(512) void attn_kernel(
    const __bf16* __restrict__ revb, const __bf16* __restrict__ fwdb,
    const float* __restrict__ attn_w, const float* __restrict__ attn_bp,
    __bf16* __restrict__ ht)
{
    const int tid = threadIdx.x;
    const int w = tid >> 6, lane = tid & 63;
    const int wid = blockIdx.x * 8 + w;      // 2048 waves: one per (i,b)
    const int i = wid >> 5, b = wid & 31;
    const int d0 = lane * 4;

    float wf[4], wr[4];
#pragma unroll
    for (int q = 0; q < 4; q++) { wf[q] = attn_w[d0 + q]; wr[q] = attn_w[256 + d0 + q]; }
    const float ab = attn_bp[0];
    const __bf16* rbase = revb + ((size_t)(i * (i + 1) / 2)) * 8192;

    float mx = -1e30f, l = 0.f;
    float cf[4] = {0,0,0,0}, cr[4] = {0,0,0,0};
    for (int t = 0; t <= i; t++) {
        bf16x4 rv4 = *(const bf16x4*)(rbase + (size_t)(t * 32 + b) * 256 + d0);
        bf16x4 fv4 = *(const bf16x4*)(fwdb + (size_t)(t * 32 + b) * 256 + d0);
        float rv[4], fv[4], s = 0.f;
#pragma unroll
        for (int q = 0; q < 4; q++) {
            rv[q] = (float)rv4[q]; fv[q] = (float)fv4[q];
            s += rv[q] * wr[q] + fv[q] * wf[q];
        }
#pragma unroll
        for (int off = 32; off > 0; off >>= 1) s += __shfl_xor(s, off);
        s += ab;
        float mn = fmaxf(mx, s);
        float sc = __expf(mx - mn);
        float p  = __expf(s - mn);
        l = l * sc + p;
#pragma unroll
        for (int q = 0; q < 4; q++) { cf[q] = cf[q] * sc + p * fv[q]; cr[q] = cr[q] * sc + p * rv[q]; }
        mx = mn;
    }
    float inv = 1.f / (l * (float)(i + 1));   // softmax denom + counts division
    __bf16* hp = ht + (size_t)(i * 32 + b) * 1024 + d0;
    const __bf16* fl = fwdb + (size_t)(i * 32 + b) * 256 + d0;
    const __bf16* rl = rbase + (size_t)(i * 32 + b) * 256 + d0;
#pragma unroll
    for (int q = 0; q < 4; q++) {
        hp[q]       = (__bf16)(cf[q] * inv);
        hp[256 + q] = (__bf16)(cr[q] * inv);
        hp[512 + q] = fl[q];
        hp[768 + q] = rl[q];
    }
}

// ---------------- launch ----------------
extern "C" void kernel_launch(void* const* d_in, const int* in_sizes, int n_in,
                              void* d_out, int out_size, void* d_ws, size_t ws_size,
                              hipStream_t stream) {
    const float* x      = (const float*)d_in[0];
    const float* W_emb  = (const float*)d_in[1];
    const float* b_emb  = (const float*)d_in[2];
    const float* Wih_f  = (const float*)d_in[3];
    const float* Whh_f  = (const float*)d_in[4];
    const float* bih_f  = (const float*)d_in[5];
    const float* bhh_f  = (const float*)d_in[6];
    const float* Wih_r  = (const float*)d_in[7];
    const float* Whh_r  = (const float*)d_in[8];
    const float* bih_r  = (const float*)d_in[9];
    const float* bhh_r  = (const float*)d_in[10];
    const float* attn_w = (const float*)d_in[11];
    const float* attn_b = (const float*)d_in[12];
    const float* W_ao   = (const float*)d_in[13];
    const float* b_ao   = (const float*)d_in[14];
    const float* W_o    = (const float*)d_in[15];
    const float* b_o    = (const float*)d_in[16];
    float* out = (float*)d_out;

    char* ws = (char*)d_ws;
    __bf16* pk_emb = (__bf16*)(ws + OFF_PK_EMB);
    __bf16* pk_ih  = (__bf16*)(ws + OFF_PK_IH);
    __bf16* pk_hhr = (__bf16*)(ws + OFF_PK_HHR);
    __bf16* pk_hhf = (__bf16*)(ws + OFF_PK_HHF);
    __bf16* pk_ao  = (__bf16*)(ws + OFF_PK_AO);
    __bf16* pk_o   = (__bf16*)(ws + OFF_PK_O);
    __bf16* day    = (__bf16*)(ws + OFF_DAY);
    float*  Gi     = (float*)(ws + OFF_GI);
    __bf16* revb   = (__bf16*)(ws + OFF_REV);
    __bf16* fwdb   = (__bf16*)(ws + OFF_FWD);
    __bf16* ht     = (__bf16*)(ws + OFF_HT);
    __bf16* tmp1   = (__bf16*)(ws + OFF_TMP1);

    pack_all<<<9152, 256, 0, stream>>>(W_emb, Wih_r, Wih_f, Whh_r, Whh_f, W_ao, W_o,
                                       pk_emb, pk_ih, pk_hhr, pk_hhf, pk_ao, pk_o);

    gemm_k<0, 4096, 256, 256><<<dim3(32, 4), 256, 0, stream>>>(x, pk_emb, day, b_emb, nullptr);
    gemm_k<1, 256, 1536, 1536><<<dim3(32, 24), 256, 0, stream>>>(day, pk_ih, Gi, bih_r, bih_f);

    gru_recurrent<<<130, 1024, 0, stream>>>(pk_hhr, pk_hhf, bhh_r, bhh_f, Gi, revb, fwdb);

    attn_kernel<<<256, 512, 0, stream>>>(revb, fwdb, attn_w, attn_b, ht);

    gemm_k<2, 1024, 256, 256><<<dim3(32, 4), 256, 0, stream>>>(ht, pk_ao, tmp1, b_ao, nullptr);
    gemm_k<3, 256, 942, 942><<<dim3(32, 15), 256, 0, stream>>>(tmp1, pk_o, out, b_o, nullptr);
}

// Round 2
// 469.340 us; speedup vs baseline: 1.3981x; 1.3981x over previous
//
#include <hip/hip_runtime.h>
#include <hip/hip_bf16.h>

// Dipole: day-emb GEMM -> fwd GRU + 64 reverse GRUs -> masked softmax attention -> 2-layer head.
// T=64 B=32 D_IN=4096 D_DAY=H=256 D_OUT=942.
//
//  k1 pack_all      : repack all weights to bf16 MFMA B-fragment layout.
//  k1b prep_bias    : bias_comb[1536] = bih (+ bhh for r,z gates) for both directions.
//  k2 gemm<0>       : day_emb = x @ W_emb^T + b_emb            (2048x4096x256, bf16 out)
//  k3 gemm<1>       : Git = day_emb @ [Wih_r|Wih_f]^T + bias   (bf16, TRANSPOSED [dir][t][g][d][b])
//  k4 gru_recurrent : 128 reverse WGs (anchor i, 16 rows) + 2 forward WGs. 512 thr / 8 waves;
//                     wave owns 32 dims -> 48 B-frags (192 VGPR) STAY IN REGISTERS
//                     (R1 failure: 1024-thr version capped at 128 VGPR -> full spill, 5.4us/step).
//  k5 attn          : per-(i,b) wave online softmax; writes h_t = [c_f|c_r|fwd|rev_last]
//  k6 gemm<2>       : tmp = h_t @ W_ao^T + b_ao                (2048x1024x256, bf16 out)
//  k7 gemm<3>       : out = sigmoid(tmp @ W_o^T + b_o)         (2048x256x942, fp32 out)

typedef __bf16 bf16x8 __attribute__((ext_vector_type(8)));
typedef __bf16 bf16x4 __attribute__((ext_vector_type(4)));
typedef float  f32x4  __attribute__((ext_vector_type(4)));

// ---------------- workspace layout (bytes) ----------------
static constexpr size_t OFF_PK_EMB = 0;                        // 256x4096 bf16    = 2097152
static constexpr size_t OFF_PK_IH  = 2097152;                  // 1536x256 bf16    =  786432
static constexpr size_t OFF_PK_HHR = 2883584;                  // 768x256 bf16     =  393216
static constexpr size_t OFF_PK_HHF = 3276800;                  // 768x256 bf16     =  393216
static constexpr size_t OFF_PK_AO  = 3670016;                  // 256x1024 bf16    =  524288
static constexpr size_t OFF_PK_O   = 4194304;                  // 960x256 bf16     =  491520
static constexpr size_t OFF_DAY    = 4685824;                  // 2048x256 bf16    = 1048576
static constexpr size_t OFF_GIT    = 5734400;                  // 2*64*3*256*32 bf16 = 6291456
static constexpr size_t OFF_BC     = 12025856;                 // 1536 f32         =    6144
static constexpr size_t OFF_REV    = 18317312;                 // 2080*32*256 bf16 = 34078720
static constexpr size_t OFF_FWD    = 52396032;                 // 64*32*256 bf16   = 1048576
static constexpr size_t OFF_HT     = 53444608;                 // 2048x1024 bf16   = 4194304
static constexpr size_t OFF_TMP1   = 57638912;                 // 2048x256 bf16    = 1048576
// total ~58.7 MB

__device__ __forceinline__ float sigf(float x) {
    return __builtin_amdgcn_rcpf(1.f + __expf(-x));
}
__device__ __forceinline__ float tanhf_(float x) {
    return 1.f - 2.f * __builtin_amdgcn_rcpf(__expf(2.f * x) + 1.f);
}

// ---------------- weight packer ----------------
// dst frag layout (per 16x16x32 mfma B operand): element
//   flat = ((nt*K32 + ks)*64 + lane)*8 + j  holds  W[nt*16 + lane%16][ks*32 + (lane/16)*8 + j]
__global__ __launch_bounds__(256) void pack_all(
    const float* __restrict__ We,  const float* __restrict__ Wir, const float* __restrict__ Wif,
    const float* __restrict__ Whr, const float* __restrict__ Whf, const float* __restrict__ Wao,
    const float* __restrict__ Wo,
    __bf16* pe, __bf16* pi, __bf16* phr, __bf16* phf, __bf16* pao, __bf16* po)
{
    int b = blockIdx.x;
    const float* src; __bf16* dst; int Nsrc, k32l, b0;
    if (b < 4096)      { src = We;  dst = pe;          Nsrc = 256; k32l = 7; b0 = 0;    }
    else if (b < 4864) { src = Wir; dst = pi;          Nsrc = 768; k32l = 3; b0 = 4096; }
    else if (b < 5632) { src = Wif; dst = pi + 196608; Nsrc = 768; k32l = 3; b0 = 4864; }
    else if (b < 6400) { src = Whr; dst = phr;         Nsrc = 768; k32l = 3; b0 = 5632; }
    else if (b < 7168) { src = Whf; dst = phf;         Nsrc = 768; k32l = 3; b0 = 6400; }
    else if (b < 8192) { src = Wao; dst = pao;         Nsrc = 256; k32l = 5; b0 = 7168; }
    else               { src = Wo;  dst = po;          Nsrc = 942; k32l = 3; b0 = 8192; }
    int e    = (b - b0) * 256 + threadIdx.x;
    int j    = e & 7;
    int lane = (e >> 3) & 63;
    int K32  = 1 << k32l;
    int K    = K32 << 5;
    int ks   = (e >> 9) & (K32 - 1);
    int nt   = e >> (9 + k32l);
    int n    = nt * 16 + (lane & 15);
    int k    = ks * 32 + ((lane >> 4) << 3) + j;
    float v  = (n < Nsrc) ? src[(size_t)n * K + k] : 0.f;
    dst[e] = (__bf16)v;
}

// bias_comb[n] for n in [0,1536): dir = n>=768, rem = n-768*dir;
// = bih_dir[rem] + (rem<512 ? bhh_dir[rem] : 0)   (n-gate bhh stays in gru kernel)
__global__ __launch_bounds__(256) void prep_bias(
    const float* __restrict__ bih_r, const float* __restrict__ bhh_r,
    const float* __restrict__ bih_f, const float* __restrict__ bhh_f,
    float* __restrict__ bc)
{
    int n = blockIdx.x * 256 + threadIdx.x;
    if (n >= 1536) return;
    int dir = (n >= 768) ? 1 : 0;
    int rem = n - dir * 768;
    const float* bi = dir ? bih_f : bih_r;
    const float* bh = dir ? bhh_f : bhh_r;
    float v = bi[rem];
    if (rem < 512) v += bh[rem];
    bc[n] = v;
}

// ---------------- generic MFMA GEMM: C[M x N] = A[M x K] @ W^T (+bias) ----------------
// MODE 0: A fp32 (x),   out bf16 (day_emb)
// MODE 1: A bf16 (day), out bf16 TRANSPOSED Git[dir][t][g][d][b]
// MODE 2: A bf16 (h_t), out bf16 (tmp1)
// MODE 3: A bf16 (tmp), out fp32 sigmoid, masked to NREAL cols
template<int MODE, int KDIM, int CSTRIDE, int NREAL>
__global__ __launch_bounds__(256) void gemm_k(
    const void* __restrict__ Ap, const __bf16* __restrict__ Bp, void* __restrict__ Cp,
    const float* __restrict__ bias)
{
    __shared__ __align__(16) __bf16 As[64][88];   // stride 88 -> benign LDS banking
    const int tid = threadIdx.x;
    const int w = tid >> 6, lane = tid & 63, c = lane & 15, quad = lane >> 4;
    const int mb = blockIdx.x, nb = blockIdx.y;
    constexpr int K32 = KDIM / 32;
    constexpr int NK  = KDIM / 64;

    f32x4 acc[4];
#pragma unroll
    for (int nt = 0; nt < 4; nt++) acc[nt] = (f32x4){0.f, 0.f, 0.f, 0.f};

    const int row = tid >> 2, kp = (tid & 3) * 16;
    float4 pf[4]; uint4 pb[2];

    auto issue = [&](int kb) {
        if constexpr (MODE == 0) {
            const float* ap = (const float*)Ap + (size_t)(mb * 64 + row) * KDIM + kb * 64 + kp;
            pf[0] = ((const float4*)ap)[0]; pf[1] = ((const float4*)ap)[1];
            pf[2] = ((const float4*)ap)[2]; pf[3] = ((const float4*)ap)[3];
        } else {
            const __bf16* ap = (const __bf16*)Ap + (size_t)(mb * 64 + row) * KDIM + kb * 64 + kp;
            pb[0] = ((const uint4*)ap)[0]; pb[1] = ((const uint4*)ap)[1];
        }
    };
    auto commit = [&]() {
        if constexpr (MODE == 0) {
            __bf16 t[16];
#pragma unroll
            for (int q = 0; q < 4; q++) {
                t[q*4+0] = (__bf16)pf[q].x; t[q*4+1] = (__bf16)pf[q].y;
                t[q*4+2] = (__bf16)pf[q].z; t[q*4+3] = (__bf16)pf[q].w;
            }
            *(uint4*)&As[row][kp]     = *(uint4*)&t[0];
            *(uint4*)&As[row][kp + 8] = *(uint4*)&t[8];
        } else {
            *(uint4*)&As[row][kp]     = pb[0];
            *(uint4*)&As[row][kp + 8] = pb[1];
        }
    };

    issue(0);
    for (int kb = 0; kb < NK; kb++) {
        commit();
        __syncthreads();
        if (kb + 1 < NK) issue(kb + 1);   // prefetch next A block; latency hidden by MFMA
#pragma unroll
        for (int kk = 0; kk < 2; kk++) {
            bf16x8 a = *(const bf16x8*)&As[w * 16 + c][kk * 32 + quad * 8];
#pragma unroll
            for (int nt = 0; nt < 4; nt++) {
                bf16x8 bfr = *(const bf16x8*)(Bp +
                    ((size_t)((nb * 4 + nt) * K32 + kb * 2 + kk) * 64 + lane) * 8);
                acc[nt] = __builtin_amdgcn_mfma_f32_16x16x32_bf16(a, bfr, acc[nt], 0, 0, 0);
            }
        }
        __syncthreads();
    }

#pragma unroll
    for (int nt = 0; nt < 4; nt++) {
        int n = nb * 64 + nt * 16 + c;
        float bv = (n < NREAL) ? bias[n] : 0.f;
#pragma unroll
        for (int r0 = 0; r0 < 4; r0++) {
            int m = mb * 64 + w * 16 + quad * 4 + r0;
            float v = acc[nt][r0] + bv;
            if constexpr (MODE == 0)      ((__bf16*)Cp)[(size_t)m * CSTRIDE + n] = (__bf16)v;
            else if constexpr (MODE == 1) {
                int dir = (n >= 768) ? 1 : 0;
                int rem = n - dir * 768;
                int g = rem >> 8, dd = rem & 255;
                int t = m >> 5, b = m & 31;
                ((__bf16*)Cp)[(size_t)((((dir * 64 + t) * 3 + g) * 256 + dd) * 32 + b)] = (__bf16)v;
            }
            else if constexpr (MODE == 2) ((__bf16*)Cp)[(size_t)m * CSTRIDE + n] = (__bf16)v;
            else { if (n < NREAL) ((float*)Cp)[(size_t)m * CSTRIDE + n] = sigf(v); }
        }
    }
}

// ---------------- recurrent GRU kernel ----------------
// grid = 130 x 512 threads (8 waves).
// bid 0..127: reverse anchor i = bid>>1, batch rows b0 = (bid&1)*16, runs i+1 steps,
//             writes rev[tri(i)*8192 + (j*32+b)*256 + d].
// bid 128/129: forward GRU halves (b0 = 0/16), 64 steps, writes fwd.
// Wave w owns h-dims [32w,32w+32) = 2 col-tiles x 3 gates = 6 mfma tiles.
// Whh B-frags: 48 x bf16x8 = 192 VGPRs, MUST stay resident (launch_bounds(512,2) -> 256 cap).
__global__ __launch_bounds__(512, 2) void gru_recurrent(
    const __bf16* __restrict__ pk_hh_r, const __bf16* __restrict__ pk_hh_f,
    const float* __restrict__ bhh_r, const float* __restrict__ bhh_f,
    const __bf16* __restrict__ Git,
    __bf16* __restrict__ revb, __bf16* __restrict__ fwdb)
{
    __shared__ __align__(16) __bf16 hbuf[2][16][264];  // row stride 264: staggers banks, b128-read clean
    const int tid = threadIdx.x;
    const int w = tid >> 6, lane = tid & 63, c = lane & 15, quad = lane >> 4;
    const int bid = blockIdx.x;
    const bool isF = (bid >= 128);
    const int ia = isF ? 63 : (bid >> 1);
    const int b0 = isF ? ((bid - 128) << 4) : ((bid & 1) << 4);
    const int steps = ia + 1;
    const __bf16* pk = isF ? pk_hh_f : pk_hh_r;
    const float* bhh = isF ? bhh_f : bhh_r;
    __bf16* outb = isF ? fwdb : (revb + ((size_t)(ia * (ia + 1) / 2)) * 8192);

    // Whh B-fragments -> registers (48 x 16B per lane = 192 VGPRs)
    bf16x8 bw[48];
#pragma unroll
    for (int g = 0; g < 3; g++)
#pragma unroll
        for (int t = 0; t < 2; t++)
#pragma unroll
            for (int kk = 0; kk < 8; kk++)
                bw[(g * 2 + t) * 8 + kk] =
                    *(const bf16x8*)(pk + (((size_t)((g * 16 + 2 * w + t) * 8 + kk)) * 64 + lane) * 8);
    float bnv[2];   // n-gate hidden bias (r,z folded into Git)
#pragma unroll
    for (int t = 0; t < 2; t++) bnv[t] = bhh[512 + (w << 5) + (t << 4) + c];

    float hreg[2][4] = {{0,0,0,0},{0,0,0,0}};
    for (int idx = tid; idx < 2 * 16 * 264; idx += 512) ((__bf16*)hbuf)[idx] = (__bf16)0.f;
    __syncthreads();

    // Git[dir][t_in][g][d][b]: per-step pointer walk (reverse: t_in = ia-j, fwd: t_in = j)
    const __bf16* gb = Git + ((size_t)(((isF ? 64 : 0) + (isF ? 0 : ia)) * 3) * 256) * 32
                     + b0 + (quad << 2);
    const long gstep = isF ? (3 * 256 * 32) : -(3 * 256 * 32);
    __bf16* go = outb + (size_t)(b0 + (quad << 2)) * 256;

    for (int j = 0; j < steps; j++) {
        const int rb = j & 1, wbuf = rb ^ 1;

        // input-side gates for this step (bf16x4 = 4 batch rows each); issued before MFMA
        bf16x4 giv[3][2];
#pragma unroll
        for (int g = 0; g < 3; g++)
#pragma unroll
            for (int t = 0; t < 2; t++)
                giv[g][t] = *(const bf16x4*)(gb + ((size_t)((g << 8) + (w << 5) + (t << 4) + c) << 5));

        f32x4 acc[3][2];
#pragma unroll
        for (int g = 0; g < 3; g++)
#pragma unroll
            for (int t = 0; t < 2; t++) acc[g][t] = (f32x4){0.f, 0.f, 0.f, 0.f};

#pragma unroll
        for (int kk = 0; kk < 8; kk++) {
            bf16x8 av = *(const bf16x8*)&hbuf[rb][c][kk * 32 + quad * 8];
#pragma unroll
            for (int g = 0; g < 3; g++)
#pragma unroll
                for (int t = 0; t < 2; t++)
                    acc[g][t] = __builtin_amdgcn_mfma_f32_16x16x32_bf16(av, bw[(g * 2 + t) * 8 + kk],
                                                                        acc[g][t], 0, 0, 0);
        }

#pragma unroll
        for (int t = 0; t < 2; t++) {
            const int d = (w << 5) + (t << 4) + c;
#pragma unroll
            for (int r0 = 0; r0 < 4; r0++) {
                float rg = sigf(acc[0][t][r0] + (float)giv[0][t][r0]);
                float zg = sigf(acc[1][t][r0] + (float)giv[1][t][r0]);
                float ng = tanhf_((float)giv[2][t][r0] + rg * (acc[2][t][r0] + bnv[t]));
                float h  = (1.f - zg) * ng + zg * hreg[t][r0];
                hreg[t][r0] = h;
                __bf16 hb = (__bf16)h;
                hbuf[wbuf][(quad << 2) + r0][d] = hb;   // broadcast for next step's A-frags
                go[(size_t)r0 * 256 + d] = hb;          // persist for attention
            }
        }
        gb += gstep;
        go += 8192;
        __syncthreads();
    }
}

// ---------------- attention (online softmax over t<=i) ----------------
__global__ __launch_bounds__(512) void attn_kernel(
    const __bf16* __restrict__ revb, const __bf16* __restrict__ fwdb,
    const float* __restrict__ attn_w, const float* __restrict__ attn_bp,
    __bf16* __restrict__ ht)
{
    const int tid = threadIdx.x;
    const int w = tid >> 6, lane = tid & 63;
    const int wid = blockIdx.x * 8 + w;      // 2048 waves: one per (i,b)
    const int i = wid >> 5, b = wid & 31;
    const int d0 = lane * 4;

    float wf[4], wr[4];
#pragma unroll
    for (int q = 0; q < 4; q++) { wf[q] = attn_w[d0 + q]; wr[q] = attn_w[256 + d0 + q]; }
    const float ab = attn_bp[0];
    const __bf16* rbase = revb + ((size_t)(i * (i + 1) / 2)) * 8192;

    float mx = -1e30f, l = 0.f;
    float cf[4] = {0,0,0,0}, cr[4] = {0,0,0,0};
    for (int t = 0; t <= i; t++) {
        bf16x4 rv4 = *(const bf16x4*)(rbase + (size_t)(t * 32 + b) * 256 + d0);
        bf16x4 fv4 = *(const bf16x4*)(fwdb + (size_t)(t * 32 + b) * 256 + d0);
        float rv[4], fv[4], s = 0.f;
#pragma unroll
        for (int q = 0; q < 4; q++) {
            rv[q] = (float)rv4[q]; fv[q] = (float)fv4[q];
            s += rv[q] * wr[q] + fv[q] * wf[q];
        }
#pragma unroll
        for (int off = 32; off > 0; off >>= 1) s += __shfl_xor(s, off);
        s += ab;
        float mn = fmaxf(mx, s);
        float sc = __expf(mx - mn);
        float p  = __expf(s - mn);
        l = l * sc + p;
#pragma unroll
        for (int q = 0; q < 4; q++) { cf[q] = cf[q] * sc + p * fv[q]; cr[q] = cr[q] * sc + p * rv[q]; }
        mx = mn;
    }
    float inv = __builtin_amdgcn_rcpf(l * (float)(i + 1));   // softmax denom + counts division
    __bf16* hp = ht + (size_t)(i * 32 + b) * 1024 + d0;
    const __bf16* fl = fwdb + (size_t)(i * 32 + b) * 256 + d0;
    const __bf16* rl = rbase + (size_t)(i * 32 + b) * 256 + d0;
#pragma unroll
    for (int q = 0; q < 4; q++) {
        hp[q]       = (__bf16)(cf[q] * inv);
        hp[256 + q] = (__bf16)(cr[q] * inv);
        hp[512 + q] = fl[q];
        hp[768 + q] = rl[q];
    }
}

// ---------------- launch ----------------
extern "C" void kernel_launch(void* const* d_in, const int* in_sizes, int n_in,
                              void* d_out, int out_size, void* d_ws, size_t ws_size,
                              hipStream_t stream) {
    const float* x      = (const float*)d_in[0];
    const float* W_emb  = (const float*)d_in[1];
    const float* b_emb  = (const float*)d_in[2];
    const float* Wih_f  = (const float*)d_in[3];
    const float* Whh_f  = (const float*)d_in[4];
    const float* bih_f  = (const float*)d_in[5];
    const float* bhh_f  = (const float*)d_in[6];
    const float* Wih_r  = (const float*)d_in[7];
    const float* Whh_r  = (const float*)d_in[8];
    const float* bih_r  = (const float*)d_in[9];
    const float* bhh_r  = (const float*)d_in[10];
    const float* attn_w = (const float*)d_in[11];
    const float* attn_b = (const float*)d_in[12];
    const float* W_ao   = (const float*)d_in[13];
    const float* b_ao   = (const float*)d_in[14];
    const float* W_o    = (const float*)d_in[15];
    const float* b_o    = (const float*)d_in[16];
    float* out = (float*)d_out;

    char* ws = (char*)d_ws;
    __bf16* pk_emb = (__bf16*)(ws + OFF_PK_EMB);
    __bf16* pk_ih  = (__bf16*)(ws + OFF_PK_IH);
    __bf16* pk_hhr = (__bf16*)(ws + OFF_PK_HHR);
    __bf16* pk_hhf = (__bf16*)(ws + OFF_PK_HHF);
    __bf16* pk_ao  = (__bf16*)(ws + OFF_PK_AO);
    __bf16* pk_o   = (__bf16*)(ws + OFF_PK_O);
    __bf16* day    = (__bf16*)(ws + OFF_DAY);
    __bf16* Git    = (__bf16*)(ws + OFF_GIT);
    float*  bc     = (float*)(ws + OFF_BC);
    __bf16* revb   = (__bf16*)(ws + OFF_REV);
    __bf16* fwdb   = (__bf16*)(ws + OFF_FWD);
    __bf16* ht     = (__bf16*)(ws + OFF_HT);
    __bf16* tmp1   = (__bf16*)(ws + OFF_TMP1);

    pack_all<<<9152, 256, 0, stream>>>(W_emb, Wih_r, Wih_f, Whh_r, Whh_f, W_ao, W_o,
                                       pk_emb, pk_ih, pk_hhr, pk_hhf, pk_ao, pk_o);
    prep_bias<<<6, 256, 0, stream>>>(bih_r, bhh_r, bih_f, bhh_f, bc);

    gemm_k<0, 4096, 256, 256><<<dim3(32, 4), 256, 0, stream>>>(x, pk_emb, day, b_emb);
    gemm_k<1, 256, 1536, 1536><<<dim3(32, 24), 256, 0, stream>>>(day, pk_ih, Git, bc);

    gru_recurrent<<<130, 512, 0, stream>>>(pk_hhr, pk_hhf, bhh_r, bhh_f, Git, revb, fwdb);

    attn_kernel<<<256, 512, 0, stream>>>(revb, fwdb, attn_w, attn_b, ht);

    gemm_k<2, 1024, 256, 256><<<dim3(32, 4), 256, 0, stream>>>(ht, pk_ao, tmp1, b_ao);
    gemm_k<3, 256, 942, 942><<<dim3(32, 15), 256, 0, stream>>>(tmp1, pk_o, out, b_o);
}

// Round 3
// 439.191 us; speedup vs baseline: 1.4941x; 1.0686x over previous
//
#include <hip/hip_runtime.h>
#include <hip/hip_bf16.h>

// Dipole: day-emb GEMM -> fwd GRU + 64 reverse GRUs -> masked softmax attention -> 2-layer head.
// T=64 B=32 D_IN=4096 D_DAY=H=256 D_OUT=942.
//
//  k1 pack_all      : repack GEMM weights to bf16 MFMA B-fragment layout.
//  k1b pack_hh_i8   : Whh -> int8 per-row-scaled MFMA B-frags (i8 16x16x64).
//  k1c prep_bias    : bias_comb[1536] = bih (+ bhh for r,z gates) both dirs.
//  k2 gemm<0>       : day_emb = x @ W_emb^T + b_emb            (2048x4096x256, bf16)
//  k3 gemm<1>       : Git = day_emb @ [Wih_r|Wih_f]^T + bias   (bf16, [dir][t][g][d][b])
//  k4 gru_recurrent : 128 reverse WGs (anchor i, 16 rows) + 2 forward WGs; 1024 thr/16 waves.
//                     Whh int8 frags = 48 VGPR/lane -> fits 128-unified cap, NO spill
//                     (R2 failure: 192 bf16 frag VGPRs vs 128 arch regs -> moves/spill, 4700cyc/step).
//                     h history in LDS, bulk b128 flush every 8 steps; lgkm-only asm barrier.
//  k5 attn          : per-(i,b) wave online softmax; h_t = [c_f|c_r|fwd|rev_last]
//  k6 gemm<2>       : tmp = h_t @ W_ao^T + b_ao                (2048x1024x256, bf16)
//  k7 gemm<3>       : out = sigmoid(tmp @ W_o^T + b_o)         (2048x256x942, fp32)

typedef __bf16 bf16x8 __attribute__((ext_vector_type(8)));
typedef __bf16 bf16x4 __attribute__((ext_vector_type(4)));
typedef float  f32x4  __attribute__((ext_vector_type(4)));
typedef int    int4v  __attribute__((ext_vector_type(4)));

// ---------------- workspace layout (bytes) ----------------
static constexpr size_t OFF_PK_EMB = 0;                        // 256x4096 bf16    = 2097152
static constexpr size_t OFF_PK_IH  = 2097152;                  // 1536x256 bf16    =  786432
static constexpr size_t OFF_WQ     = 2883584;                  // 2x768x256 int8   =  393216
static constexpr size_t OFF_WSC    = 3276800;                  // 1536 f32         =    6144
static constexpr size_t OFF_PK_AO  = 3670016;                  // 256x1024 bf16    =  524288
static constexpr size_t OFF_PK_O   = 4194304;                  // 960x256 bf16     =  491520
static constexpr size_t OFF_DAY    = 4685824;                  // 2048x256 bf16    = 1048576
static constexpr size_t OFF_GIT    = 5734400;                  // 2*64*3*256*32 bf16 = 6291456
static constexpr size_t OFF_BC     = 12025856;                 // 1536 f32         =    6144
static constexpr size_t OFF_REV    = 18317312;                 // 2080*32*256 bf16 = 34078720
static constexpr size_t OFF_FWD    = 52396032;                 // 64*32*256 bf16   = 1048576
static constexpr size_t OFF_HT     = 53444608;                 // 2048x1024 bf16   = 4194304
static constexpr size_t OFF_TMP1   = 57638912;                 // 2048x256 bf16    = 1048576
// total ~58.7 MB

__device__ __forceinline__ float sigf(float x) {
    return __builtin_amdgcn_rcpf(1.f + __expf(-x));
}
__device__ __forceinline__ float tanhf_(float x) {
    return 1.f - 2.f * __builtin_amdgcn_rcpf(__expf(2.f * x) + 1.f);
}

// lgkmcnt-only barrier: skips the vmcnt(0) drain __syncthreads would force.
#define LDS_BARRIER() asm volatile("s_waitcnt lgkmcnt(0)\n\ts_barrier" ::: "memory")

// ---------------- bf16 weight packer (GEMM weights) ----------------
// frag layout: flat = ((nt*K32 + ks)*64 + lane)*8 + j holds W[nt*16+lane%16][ks*32+(lane/16)*8+j]
__global__ __launch_bounds__(256) void pack_all(
    const float* __restrict__ We,  const float* __restrict__ Wir, const float* __restrict__ Wif,
    const float* __restrict__ Wao, const float* __restrict__ Wo,
    __bf16* pe, __bf16* pi, __bf16* pao, __bf16* po)
{
    int b = blockIdx.x;
    const float* src; __bf16* dst; int Nsrc, k32l, b0;
    if (b < 4096)      { src = We;  dst = pe;          Nsrc = 256; k32l = 7; b0 = 0;    }
    else if (b < 4864) { src = Wir; dst = pi;          Nsrc = 768; k32l = 3; b0 = 4096; }
    else if (b < 5632) { src = Wif; dst = pi + 196608; Nsrc = 768; k32l = 3; b0 = 4864; }
    else if (b < 6656) { src = Wao; dst = pao;         Nsrc = 256; k32l = 5; b0 = 5632; }
    else               { src = Wo;  dst = po;          Nsrc = 942; k32l = 3; b0 = 6656; }
    int e    = (b - b0) * 256 + threadIdx.x;
    int j    = e & 7;
    int lane = (e >> 3) & 63;
    int K32  = 1 << k32l;
    int K    = K32 << 5;
    int ks   = (e >> 9) & (K32 - 1);
    int nt   = e >> (9 + k32l);
    int n    = nt * 16 + (lane & 15);
    int k    = ks * 32 + ((lane >> 4) << 3) + j;
    float v  = (n < Nsrc) ? src[(size_t)n * K + k] : 0.f;
    dst[e] = (__bf16)v;
}

// ---------------- Whh int8 packer ----------------
// i8 16x16x64 B-frag: element (n,k): lane = (n&15)|(((k>>4)&3)<<4), byte j = k&15;
// flat byte = dir*196608 + ((n>>4)*4 + (k>>6))*1024 + lane*16 + j.  scale[dir*768+n] = rowmax/127.
__global__ __launch_bounds__(64) void pack_hh_i8(
    const float* __restrict__ Whr, const float* __restrict__ Whf,
    signed char* __restrict__ wq, float* __restrict__ wscale)
{
    int b = blockIdx.x;               // 1536: dir*768 + n
    int dir = (b >= 768) ? 1 : 0;
    int n = b - dir * 768;
    const float* src = (dir ? Whf : Whr) + (size_t)n * 256;
    int t = threadIdx.x;
    float4 wv = ((const float4*)src)[t];     // k = 4t..4t+3
    float m = fmaxf(fmaxf(fabsf(wv.x), fabsf(wv.y)), fmaxf(fabsf(wv.z), fabsf(wv.w)));
#pragma unroll
    for (int off = 32; off > 0; off >>= 1) m = fmaxf(m, __shfl_xor(m, off));
    float s_step = m * (1.f / 127.f);
    float inv = 127.f / m;
    int q0 = (int)__builtin_rintf(wv.x * inv);
    int q1 = (int)__builtin_rintf(wv.y * inv);
    int q2 = (int)__builtin_rintf(wv.z * inv);
    int q3 = (int)__builtin_rintf(wv.w * inv);
    int pk = (q0 & 0xff) | ((q1 & 0xff) << 8) | ((q2 & 0xff) << 16) | ((q3 & 0xff) << 24);
    int dlane = (n & 15) | (((t >> 2) & 3) << 4);
    size_t byte = (size_t)dir * 196608 + ((size_t)(n >> 4) * 4 + (t >> 4)) * 1024
                + (size_t)dlane * 16 + (t & 3) * 4;
    *(int*)(wq + byte) = pk;
    if (t == 0) wscale[b] = s_step;
}

// bias_comb[n], n in [0,1536): dir = n>=768; = bih_dir[rem] + (rem<512 ? bhh_dir[rem] : 0)
__global__ __launch_bounds__(256) void prep_bias(
    const float* __restrict__ bih_r, const float* __restrict__ bhh_r,
    const float* __restrict__ bih_f, const float* __restrict__ bhh_f,
    float* __restrict__ bc)
{
    int n = blockIdx.x * 256 + threadIdx.x;
    if (n >= 1536) return;
    int dir = (n >= 768) ? 1 : 0;
    int rem = n - dir * 768;
    const float* bi = dir ? bih_f : bih_r;
    const float* bh = dir ? bhh_f : bhh_r;
    float v = bi[rem];
    if (rem < 512) v += bh[rem];
    bc[n] = v;
}

// ---------------- generic MFMA GEMM: C[M x N] = A[M x K] @ W^T (+bias) ----------------
template<int MODE, int KDIM, int CSTRIDE, int NREAL>
__global__ __launch_bounds__(256) void gemm_k(
    const void* __restrict__ Ap, const __bf16* __restrict__ Bp, void* __restrict__ Cp,
    const float* __restrict__ bias)
{
    __shared__ __align__(16) __bf16 As[64][88];
    const int tid = threadIdx.x;
    const int w = tid >> 6, lane = tid & 63, c = lane & 15, quad = lane >> 4;
    const int mb = blockIdx.x, nb = blockIdx.y;
    constexpr int K32 = KDIM / 32;
    constexpr int NK  = KDIM / 64;

    f32x4 acc[4];
#pragma unroll
    for (int nt = 0; nt < 4; nt++) acc[nt] = (f32x4){0.f, 0.f, 0.f, 0.f};

    const int row = tid >> 2, kp = (tid & 3) * 16;
    float4 pf[4]; uint4 pb[2];

    auto issue = [&](int kb) {
        if constexpr (MODE == 0) {
            const float* ap = (const float*)Ap + (size_t)(mb * 64 + row) * KDIM + kb * 64 + kp;
            pf[0] = ((const float4*)ap)[0]; pf[1] = ((const float4*)ap)[1];
            pf[2] = ((const float4*)ap)[2]; pf[3] = ((const float4*)ap)[3];
        } else {
            const __bf16* ap = (const __bf16*)Ap + (size_t)(mb * 64 + row) * KDIM + kb * 64 + kp;
            pb[0] = ((const uint4*)ap)[0]; pb[1] = ((const uint4*)ap)[1];
        }
    };
    auto commit = [&]() {
        if constexpr (MODE == 0) {
            __bf16 t[16];
#pragma unroll
            for (int q = 0; q < 4; q++) {
                t[q*4+0] = (__bf16)pf[q].x; t[q*4+1] = (__bf16)pf[q].y;
                t[q*4+2] = (__bf16)pf[q].z; t[q*4+3] = (__bf16)pf[q].w;
            }
            *(uint4*)&As[row][kp]     = *(uint4*)&t[0];
            *(uint4*)&As[row][kp + 8] = *(uint4*)&t[8];
        } else {
            *(uint4*)&As[row][kp]     = pb[0];
            *(uint4*)&As[row][kp + 8] = pb[1];
        }
    };

    issue(0);
    for (int kb = 0; kb < NK; kb++) {
        commit();
        __syncthreads();
        if (kb + 1 < NK) issue(kb + 1);
#pragma unroll
        for (int kk = 0; kk < 2; kk++) {
            bf16x8 a = *(const bf16x8*)&As[w * 16 + c][kk * 32 + quad * 8];
#pragma unroll
            for (int nt = 0; nt < 4; nt++) {
                bf16x8 bfr = *(const bf16x8*)(Bp +
                    ((size_t)((nb * 4 + nt) * K32 + kb * 2 + kk) * 64 + lane) * 8);
                acc[nt] = __builtin_amdgcn_mfma_f32_16x16x32_bf16(a, bfr, acc[nt], 0, 0, 0);
            }
        }
        __syncthreads();
    }

#pragma unroll
    for (int nt = 0; nt < 4; nt++) {
        int n = nb * 64 + nt * 16 + c;
        float bv = (n < NREAL) ? bias[n] : 0.f;
#pragma unroll
        for (int r0 = 0; r0 < 4; r0++) {
            int m = mb * 64 + w * 16 + quad * 4 + r0;
            float v = acc[nt][r0] + bv;
            if constexpr (MODE == 0)      ((__bf16*)Cp)[(size_t)m * CSTRIDE + n] = (__bf16)v;
            else if constexpr (MODE == 1) {
                int dir = (n >= 768) ? 1 : 0;
                int rem = n - dir * 768;
                int g = rem >> 8, dd = rem & 255;
                int t = m >> 5, b = m & 31;
                ((__bf16*)Cp)[(size_t)((((dir * 64 + t) * 3 + g) * 256 + dd) * 32 + b)] = (__bf16)v;
            }
            else if constexpr (MODE == 2) ((__bf16*)Cp)[(size_t)m * CSTRIDE + n] = (__bf16)v;
            else { if (n < NREAL) ((float*)Cp)[(size_t)m * CSTRIDE + n] = sigf(v); }
        }
    }
}

// ---------------- recurrent GRU kernel ----------------
// grid = 130 x 1024 threads (16 waves). bid 0/1: forward halves (64 steps).
// bid 2..129: reverse anchor ia = 63-((bid-2)>>1), b-half b0 = (bid&1)*16 (longest chains first).
// Wave w owns 16 h-dims [16w,16w+16) x 3 gates. Whh int8 frags: 3x4 int4v = 48 VGPR.
// h-state fp32 in VGPRs; int8 h broadcast via LDS dbuf; bf16 h history in LDS, flushed
// every 8 steps with b128 stores.
__global__ __launch_bounds__(1024, 4) void gru_recurrent(
    const signed char* __restrict__ wq, const float* __restrict__ wscale,
    const float* __restrict__ bhh_r, const float* __restrict__ bhh_f,
    const __bf16* __restrict__ Git,
    __bf16* __restrict__ revb, __bf16* __restrict__ fwdb)
{
    __shared__ __align__(16) signed char hbuf[2][16][272];   // [buf][batch row][h dim]
    __shared__ __align__(16) __bf16 hist[8][4096];           // [step%8][row*256+dim]
    const int tid = threadIdx.x;
    const int w = tid >> 6, lane = tid & 63, c = lane & 15, quad = lane >> 4;
    const int bid = blockIdx.x;
    const bool isF = (bid < 2);
    const int ia = isF ? 63 : (63 - ((bid - 2) >> 1));
    const int b0 = (bid & 1) << 4;
    const int steps = ia + 1;
    const float* bhh = isF ? bhh_f : bhh_r;
    __bf16* outb = isF ? fwdb : (revb + ((size_t)(ia * (ia + 1) / 2)) * 8192);

    // Whh int8 B-frags (dir-selected): tile = g*16 + w, 4 K-steps, 16 B/lane each
    const int4v* pw = (const int4v*)(wq + (isF ? 196608 : 0));
    int4v bw[3][4];
#pragma unroll
    for (int g = 0; g < 3; g++)
#pragma unroll
        for (int ks = 0; ks < 4; ks++)
            bw[g][ks] = pw[(size_t)((g * 16 + w) * 4 + ks) * 64 + lane];
    float sc[3];
#pragma unroll
    for (int g = 0; g < 3; g++)
        sc[g] = wscale[(isF ? 768 : 0) + g * 256 + (w << 4) + c] * (1.f / 127.f);
    const float bnv = bhh[512 + (w << 4) + c];   // n-gate hidden bias (r,z folded into Git)

    float hreg[4] = {0.f, 0.f, 0.f, 0.f};
    for (int idx = tid; idx < 2 * 16 * 272 / 4; idx += 1024) ((int*)hbuf)[idx] = 0;
    __syncthreads();

    // Git[dir][t][g][d][b]; per-lane offsets (g<<8)+(w<<4)+c over dims, b0+quad*4 over batch
    const __bf16* gb = Git + (size_t)(isF ? 64 : ia) * 24576 + b0 + (quad << 2);
    const long gstep = isF ? 24576 : -24576;

    auto flush = [&](int jbase, int cnt) {
        int s = tid >> 7;
        if (s < cnt) {
            const uint4* src = (const uint4*)((const char*)&hist[s][0] + (tid & 127) * 64);
            uint4 v0 = src[0], v1 = src[1], v2 = src[2], v3 = src[3];
            uint4* dst = (uint4*)(outb + (size_t)(jbase + s) * 8192 + b0 * 256 + (tid & 127) * 32);
            dst[0] = v0; dst[1] = v1; dst[2] = v2; dst[3] = v3;
        }
    };

    bf16x4 gcur[3], gnxt[3];
#pragma unroll
    for (int g = 0; g < 3; g++)
        gcur[g] = *(const bf16x4*)(gb + ((size_t)((g << 8) + (w << 4) + c) << 5));

    for (int j = 0; j < steps; j++) {
        const int rb = j & 1, wbuf = rb ^ 1;

        if (j + 1 < steps) {
            const __bf16* gn = gb + gstep;
#pragma unroll
            for (int g = 0; g < 3; g++)
                gnxt[g] = *(const bf16x4*)(gn + ((size_t)((g << 8) + (w << 4) + c) << 5));
        }

        int4v a0 = {0,0,0,0}, a1 = {0,0,0,0}, a2 = {0,0,0,0};
#pragma unroll
        for (int ks = 0; ks < 4; ks++) {
            int4v av = *(const int4v*)&hbuf[rb][c][ks * 64 + quad * 16];
            a0 = __builtin_amdgcn_mfma_i32_16x16x64_i8(av, bw[0][ks], a0, 0, 0, 0);
            a1 = __builtin_amdgcn_mfma_i32_16x16x64_i8(av, bw[1][ks], a1, 0, 0, 0);
            a2 = __builtin_amdgcn_mfma_i32_16x16x64_i8(av, bw[2][ks], a2, 0, 0, 0);
        }

        const int d = (w << 4) + c;
        const int hs = j & 7;
#pragma unroll
        for (int r0 = 0; r0 < 4; r0++) {
            float rg = sigf((float)a0[r0] * sc[0] + (float)gcur[0][r0]);
            float zg = sigf((float)a1[r0] * sc[1] + (float)gcur[1][r0]);
            float ng = tanhf_((float)gcur[2][r0] + rg * ((float)a2[r0] * sc[2] + bnv));
            float h  = ng + zg * (hreg[r0] - ng);
            hreg[r0] = h;
            int row = (quad << 2) + r0;
            hbuf[wbuf][row][d] = (signed char)(int)__builtin_rintf(h * 127.f);
            hist[hs][row * 256 + d] = (__bf16)h;
        }
        LDS_BARRIER();
        if (hs == 7) {                     // hist full: bulk flush, then re-sync
            flush(j - 7, 8);
            LDS_BARRIER();
        }
        gb += gstep;
#pragma unroll
        for (int g = 0; g < 3; g++) gcur[g] = gnxt[g];
    }
    int rem = steps & 7;
    if (rem) flush(steps - rem, rem);
}

// ---------------- attention (online softmax over t<=i) ----------------
__global__ __launch_bounds__(512) void attn_kernel(
    const __bf16* __restrict__ revb, const __bf16* __restrict__ fwdb,
    const float* __restrict__ attn_w, const float* __restrict__ attn_bp,
    __bf16* __restrict__ ht)
{
    const int tid = threadIdx.x;
    const int w = tid >> 6, lane = tid & 63;
    const int wid = blockIdx.x * 8 + w;      // 2048 waves: one per (i,b)
    const int i = wid >> 5, b = wid & 31;
    const int d0 = lane * 4;

    float wf[4], wr[4];
#pragma unroll
    for (int q = 0; q < 4; q++) { wf[q] = attn_w[d0 + q]; wr[q] = attn_w[256 + d0 + q]; }
    const float ab = attn_bp[0];
    const __bf16* rbase = revb + ((size_t)(i * (i + 1) / 2)) * 8192;

    float mx = -1e30f, l = 0.f;
    float cf[4] = {0,0,0,0}, cr[4] = {0,0,0,0};
    for (int t = 0; t <= i; t++) {
        bf16x4 rv4 = *(const bf16x4*)(rbase + (size_t)(t * 32 + b) * 256 + d0);
        bf16x4 fv4 = *(const bf16x4*)(fwdb + (size_t)(t * 32 + b) * 256 + d0);
        float rv[4], fv[4], s = 0.f;
#pragma unroll
        for (int q = 0; q < 4; q++) {
            rv[q] = (float)rv4[q]; fv[q] = (float)fv4[q];
            s += rv[q] * wr[q] + fv[q] * wf[q];
        }
#pragma unroll
        for (int off = 32; off > 0; off >>= 1) s += __shfl_xor(s, off);
        s += ab;
        float mn = fmaxf(mx, s);
        float scale = __expf(mx - mn);
        float p  = __expf(s - mn);
        l = l * scale + p;
#pragma unroll
        for (int q = 0; q < 4; q++) { cf[q] = cf[q] * scale + p * fv[q]; cr[q] = cr[q] * scale + p * rv[q]; }
        mx = mn;
    }
    float inv = __builtin_amdgcn_rcpf(l * (float)(i + 1));
    __bf16* hp = ht + (size_t)(i * 32 + b) * 1024 + d0;
    const __bf16* fl = fwdb + (size_t)(i * 32 + b) * 256 + d0;
    const __bf16* rl = rbase + (size_t)(i * 32 + b) * 256 + d0;
#pragma unroll
    for (int q = 0; q < 4; q++) {
        hp[q]       = (__bf16)(cf[q] * inv);
        hp[256 + q] = (__bf16)(cr[q] * inv);
        hp[512 + q] = fl[q];
        hp[768 + q] = rl[q];
    }
}

// ---------------- launch ----------------
extern "C" void kernel_launch(void* const* d_in, const int* in_sizes, int n_in,
                              void* d_out, int out_size, void* d_ws, size_t ws_size,
                              hipStream_t stream) {
    const float* x      = (const float*)d_in[0];
    const float* W_emb  = (const float*)d_in[1];
    const float* b_emb  = (const float*)d_in[2];
    const float* Wih_f  = (const float*)d_in[3];
    const float* Whh_f  = (const float*)d_in[4];
    const float* bih_f  = (const float*)d_in[5];
    const float* bhh_f  = (const float*)d_in[6];
    const float* Wih_r  = (const float*)d_in[7];
    const float* Whh_r  = (const float*)d_in[8];
    const float* bih_r  = (const float*)d_in[9];
    const float* bhh_r  = (const float*)d_in[10];
    const float* attn_w = (const float*)d_in[11];
    const float* attn_b = (const float*)d_in[12];
    const float* W_ao   = (const float*)d_in[13];
    const float* b_ao   = (const float*)d_in[14];
    const float* W_o    = (const float*)d_in[15];
    const float* b_o    = (const float*)d_in[16];
    float* out = (float*)d_out;

    char* ws = (char*)d_ws;
    __bf16* pk_emb = (__bf16*)(ws + OFF_PK_EMB);
    __bf16* pk_ih  = (__bf16*)(ws + OFF_PK_IH);
    signed char* wq = (signed char*)(ws + OFF_WQ);
    float*  wsc    = (float*)(ws + OFF_WSC);
    __bf16* pk_ao  = (__bf16*)(ws + OFF_PK_AO);
    __bf16* pk_o   = (__bf16*)(ws + OFF_PK_O);
    __bf16* day    = (__bf16*)(ws + OFF_DAY);
    __bf16* Git    = (__bf16*)(ws + OFF_GIT);
    float*  bc     = (float*)(ws + OFF_BC);
    __bf16* revb   = (__bf16*)(ws + OFF_REV);
    __bf16* fwdb   = (__bf16*)(ws + OFF_FWD);
    __bf16* ht     = (__bf16*)(ws + OFF_HT);
    __bf16* tmp1   = (__bf16*)(ws + OFF_TMP1);

    pack_all<<<7616, 256, 0, stream>>>(W_emb, Wih_r, Wih_f, W_ao, W_o,
                                       pk_emb, pk_ih, pk_ao, pk_o);
    pack_hh_i8<<<1536, 64, 0, stream>>>(Whh_r, Whh_f, wq, wsc);
    prep_bias<<<6, 256, 0, stream>>>(bih_r, bhh_r, bih_f, bhh_f, bc);

    gemm_k<0, 4096, 256, 256><<<dim3(32, 4), 256, 0, stream>>>(x, pk_emb, day, b_emb);
    gemm_k<1, 256, 1536, 1536><<<dim3(32, 24), 256, 0, stream>>>(day, pk_ih, Git, bc);

    gru_recurrent<<<130, 1024, 0, stream>>>(wq, wsc, bhh_r, bhh_f, Git, revb, fwdb);

    attn_kernel<<<256, 512, 0, stream>>>(revb, fwdb, attn_w, attn_b, ht);

    gemm_k<2, 1024, 256, 256><<<dim3(32, 4), 256, 0, stream>>>(ht, pk_ao, tmp1, b_ao);
    gemm_k<3, 256, 942, 942><<<dim3(32, 15), 256, 0, stream>>>(tmp1, pk_o, out, b_o);
}